// Round 10
// baseline (424.949 us; speedup 1.0000x reference)
//
#include <hip/hip_runtime.h>
#include <hip/hip_fp16.h>

#define N_NODES 100000
#define N_EDGES 1600000
#define D_IN 25
#define D_OUT 50
#define NBKT 782        // ceil(N_NODES/128) coarse buckets (dst>>7)
#define EPB 8192        // edges per block in scatter pass
#define NBLK_E 196      // ceil(N_EDGES/EPB)
#define NBLK_SCAT (3 * NBLK_E)
#define NBLK_TRANS 1563 // ceil(N_NODES/64)
#define BSTR 2560       // fixed bucket stride (mean 2048 + >10 sigma)
#define CAP 2944        // LDS sorted-list capacity (BSTR + 128*3 padding)
#define TSTR 32
#define OSTR 72

typedef __attribute__((ext_vector_type(8))) _Float16 half8;
typedef __attribute__((ext_vector_type(2))) _Float16 h2;
typedef __attribute__((ext_vector_type(4))) float float4v;

__device__ __forceinline__ float lrelu(float x, float a) { return fmaxf(x, a * x); }
__device__ __forceinline__ h2 bch2(unsigned u) { return __builtin_bit_cast(h2, u); }

// ---------------- pack: head B-fragments + transform weights + biases + zeroing --
// wpkAll: [0:25600) proj  [25600:40960) cls1  [40960:44032) cls2  [44032:44544) cls3
//         [44544:56832) transform 6 mats x 4 chunks x 512
// biasPad: [0:304) head; [304:688) transform 6 x 64
// extra ranges: dummy zero row (64 halves), bcur3 zeroing (3*NBKT words)
__device__ __forceinline__ void pack_seg(
    const float* __restrict__ W, unsigned short* __restrict__ outp,
    int K, int O, int NKS, int idx)
{
    int f = idx >> 9, r = idx & 511;
    int l = r >> 3, j = r & 7;
    int ot = f / NKS, ks = f - ot * NKS;
    int k = ks * 32 + (l >> 4) * 8 + j;
    int o = ot * 16 + (l & 15);
    float val = (k < K && o < O) ? W[k * O + o] : 0.f;
    outp[idx] = __half_as_ushort(__float2half_rn(val));
}

__global__ __launch_bounds__(256) void pack_all_kernel(
    const float* __restrict__ projW, const float* __restrict__ W1,
    const float* __restrict__ W2, const float* __restrict__ W3,
    const float* __restrict__ b0, const float* __restrict__ b1,
    const float* __restrict__ b2, const float* __restrict__ b3,
    const float* __restrict__ Wl0, const float* __restrict__ Wr0,
    const float* __restrict__ Wl1, const float* __restrict__ Wr1,
    const float* __restrict__ Wl2, const float* __restrict__ Wr2,
    const float* __restrict__ bl0, const float* __restrict__ br0,
    const float* __restrict__ bl1, const float* __restrict__ br1,
    const float* __restrict__ bl2, const float* __restrict__ br2,
    unsigned short* __restrict__ wpkAll, float* __restrict__ biasPad,
    __half* __restrict__ xl3, unsigned* __restrict__ bcur3)
{
    int gid = blockIdx.x * 256 + threadIdx.x;
    if (gid < 25600) pack_seg(projW, wpkAll, 150, 150, 5, gid);
    else if (gid < 40960) pack_seg(W1, wpkAll + 25600, 150, 75, 5, gid - 25600);
    else if (gid < 44032) pack_seg(W2, wpkAll + 40960, 75, 30, 3, gid - 40960);
    else if (gid < 44544) pack_seg(W3, wpkAll + 44032, 30, 2, 1, gid - 44032);
    else if (gid < 56832) {
        int t = gid - 44544;
        int mat = t >> 11, idx = t & 2047;
        const float* Wm = (mat == 0) ? Wl0 : (mat == 1) ? Wr0 : (mat == 2) ? Wl1
                        : (mat == 3) ? Wr1 : (mat == 4) ? Wl2 : Wr2;
        int ot = idx >> 9, r = idx & 511;
        int l = r >> 3, j = r & 7;
        int k = (l >> 4) * 8 + j;
        int o = ot * 16 + (l & 15);
        float val = (k < D_IN && o < D_OUT) ? Wm[k * D_OUT + o] : 0.f;
        wpkAll[44544 + t] = __half_as_ushort(__float2half_rn(val));
    } else if (gid < 57520) {
        int t = gid - 56832;
        float v;
        if (t < 304) {
            if (t < 160) v = (t < 150) ? b0[t] : 0.f;
            else if (t < 256) { int i = t - 160; v = (i < 75) ? b1[i] : 0.f; }
            else if (t < 288) { int i = t - 256; v = (i < 30) ? b2[i] : 0.f; }
            else { int i = t - 288; v = (i < 2) ? b3[i] : 0.f; }
        } else {
            int ii = t - 304;
            int mat = ii >> 6, o = ii & 63;
            const float* bm = (mat == 0) ? bl0 : (mat == 1) ? br0 : (mat == 2) ? bl1
                            : (mat == 3) ? br1 : (mat == 4) ? bl2 : br2;
            v = (o < D_OUT) ? bm[o] : 0.f;
        }
        biasPad[t] = v;
    } else if (gid < 57584) {
        // zero row at absolute row 3*N_NODES: dummy-edge gather target
        xl3[(size_t)3 * N_NODES * 64 + (gid - 57520)] = __ushort_as_half((unsigned short)0);
    } else if (gid < 57584 + 3 * NBKT) {
        bcur3[gid - 57584] = 0u;    // replaces hipMemsetAsync
    }
}

// ---------------- fused prep: bucket scatter + MFMA node transform ---------------
// blocks [0, NBLK_SCAT): edge scatter (tag = bx/NBLK_E)
// blocks [NBLK_SCAT, NBLK_SCAT+NBLK_TRANS): node transform (64 nodes/block)
struct ScatSmem { unsigned h[NBKT]; unsigned cur[NBKT]; };
struct TransSmem { _Float16 sX[64 * TSTR]; _Float16 sO[4][16 * OSTR]; };

__global__ __launch_bounds__(256) void prep_kernel(
    const int* __restrict__ eip, const int* __restrict__ eis, const int* __restrict__ eiv,
    unsigned* __restrict__ bcur3, unsigned* __restrict__ bucketed3,
    const float* __restrict__ x,
    const unsigned short* __restrict__ wpkAll, const float* __restrict__ biasPad,
    __half* __restrict__ xl3, __half* __restrict__ xr3)
{
    __shared__ union { ScatSmem s; TransSmem t; } u;
    int tid = threadIdx.x;
    int bx = blockIdx.x;
    if (bx < NBLK_SCAT) {
        // -------- edge scatter --------
        int t = bx / NBLK_E;
        int blk = bx - t * NBLK_E;
        const int* ei = (t == 0) ? eip : ((t == 1) ? eis : eiv);
        unsigned* bcur = bcur3 + t * NBKT;
        unsigned* bucketed = bucketed3 + (size_t)t * NBKT * BSTR;
        unsigned* h = u.s.h;
        unsigned* cur = u.s.cur;
        for (int b = tid; b < NBKT; b += 256) h[b] = 0;
        __syncthreads();
#pragma unroll
        for (int i = 0; i < EPB / 256; ++i) {
            int e = blk * EPB + i * 256 + tid;
            if (e < N_EDGES) atomicAdd(&h[ei[N_EDGES + e] >> 7], 1u);
        }
        __syncthreads();
        for (int b = tid; b < NBKT; b += 256)
            cur[b] = (unsigned)b * BSTR + (h[b] ? atomicAdd(&bcur[b], h[b]) : 0u);
        __syncthreads();
#pragma unroll
        for (int i = 0; i < EPB / 256; ++i) {
            int e = blk * EPB + i * 256 + tid;
            if (e < N_EDGES) {
                unsigned s = (unsigned)ei[e];
                unsigned d = (unsigned)ei[N_EDGES + e];
                unsigned b = d >> 7;
                unsigned r = atomicAdd(&cur[b], 1u);
                if (r < (b + 1u) * BSTR)           // overflow guard (>10-sigma)
                    bucketed[r] = ((d & 127u) << 17) | s;
            }
        }
    } else {
        // -------- node transform: 6 mats via 16x16x32 f16 MFMA --------
        int g0 = (bx - NBLK_SCAT) * 64;
        _Float16* sX = u.t.sX;
        for (int i = tid; i < 64 * D_IN; i += 256) {
            int r = i / D_IN, c = i - r * D_IN;
            int gr = g0 + r;
            sX[r * TSTR + c] = (gr < N_NODES) ? (_Float16)x[(size_t)gr * D_IN + c] : (_Float16)0.f;
        }
        for (int i = tid; i < 64 * 7; i += 256) {
            int r = i / 7, c = D_IN + (i - r * 7);
            sX[r * TSTR + c] = (_Float16)0.f;
        }
        __syncthreads();
        int w = tid >> 6, l = tid & 63;
        int lm = l & 15, q = l >> 4;
        half8 a = *(const half8*)(sX + (w * 16 + lm) * TSTR + q * 8);
        const unsigned short* wT = wpkAll + 44544;
#pragma unroll
        for (int mat = 0; mat < 6; ++mat) {
            float4v acc[4];
#pragma unroll
            for (int ot = 0; ot < 4; ++ot) {
                half8 b = *(const half8*)(wT + (mat * 4 + ot) * 512 + l * 8);
                float4v z = {0.f, 0.f, 0.f, 0.f};
                acc[ot] = __builtin_amdgcn_mfma_f32_16x16x32_f16(a, b, z, 0, 0, 0);
            }
#pragma unroll
            for (int ot = 0; ot < 4; ++ot) {
                float bv = biasPad[304 + mat * 64 + ot * 16 + lm];
#pragma unroll
                for (int r = 0; r < 4; ++r)
                    u.t.sO[w][(q * 4 + r) * OSTR + ot * 16 + lm] = (_Float16)(acc[ot][r] + bv);
            }
            __half* dst = ((mat & 1) ? xr3 : xl3) + (size_t)(mat >> 1) * N_NODES * 64;
#pragma unroll
            for (int it = 0; it < 2; ++it) {
                int idx = it * 64 + l;
                int rr = idx >> 3, cc = idx & 7;
                int gr = g0 + w * 16 + rr;
                if (gr < N_NODES) {
                    uint4 v = *(const uint4*)&u.t.sO[w][rr * OSTR + cc * 8];
                    *(uint4*)&dst[(size_t)gr * 64 + cc * 8] = v;
                }
            }
        }
    }
}

// ---------------- fused fine-sort + GATv2 aggregation ----------------------------
// One block per (bucket of 128 dsts, tag). srcsL holds byte offsets (flag bit 0).
// att pre-scaled by log2(e): weights via exp2.
__device__ __forceinline__ float edge_score8(uint4 u, const h2* xr, const h2* at)
{
    const h2 k2 = {(_Float16)0.2f, (_Float16)0.2f};
    float acc = 0.f;
    unsigned uu[4] = {u.x, u.y, u.z, u.w};
#pragma unroll
    for (int i = 0; i < 4; ++i) {
        h2 m = bch2(uu[i]) + xr[i];
        m = __builtin_elementwise_max(m, m * k2);
        acc = __builtin_amdgcn_fdot2(m, at[i], acc, false);
    }
    return acc;
}
__device__ __forceinline__ void accum8(float2* O, float w, uint4 u)
{
    unsigned uu[4] = {u.x, u.y, u.z, u.w};
#pragma unroll
    for (int i = 0; i < 4; ++i) {
        h2 xv = bch2(uu[i]);
        O[i].x += w * (float)xv[0];
        O[i].y += w * (float)xv[1];
    }
}

__global__ __launch_bounds__(256) void bkt_gat_kernel(
    const unsigned* __restrict__ bucketed3, const unsigned* __restrict__ bcur3,
    const __half* __restrict__ xl3, const __half* __restrict__ xr3,
    const float* __restrict__ att0, const float* __restrict__ att1, const float* __restrict__ att2,
    const float* __restrict__ bo0, const float* __restrict__ bo1, const float* __restrict__ bo2,
    __half* __restrict__ h16)
{
    int tag = blockIdx.y, b = blockIdx.x;
    const unsigned* bucketed = bucketed3 + (size_t)tag * NBKT * BSTR + (size_t)b * BSTR;
    const char* xlb = (const char*)xl3 + (size_t)tag * N_NODES * 128;
    const uint4* xr4 = (const uint4*)xr3 + (size_t)tag * N_NODES * 8;
    const float* att = (tag == 0) ? att0 : (tag == 1) ? att1 : att2;
    const float* bo  = (tag == 0) ? bo0  : (tag == 1) ? bo1  : bo2;
    int col0 = tag * 50;

    __shared__ unsigned hist[128];
    __shared__ unsigned dstart[129];
    __shared__ unsigned cur[128];
    __shared__ unsigned srcsL[CAP];
    __shared__ unsigned nextD;
    int tid = threadIdx.x;
    unsigned cnt = bcur3[tag * NBKT + b];
    if (cnt > BSTR) cnt = BSTR;
    if (tid < 128) hist[tid] = 0;
    if (tid == 0) nextD = 0;
    __syncthreads();
    for (unsigned i = tid; i < cnt; i += 256) atomicAdd(&hist[bucketed[i] >> 17], 1u);
    __syncthreads();
    unsigned c = 0, pc = 0;
    if (tid < 128) {
        c = hist[tid];
        pc = (c + 3u) & ~3u;          // pad each dst's list to multiple of 4
        hist[tid] = pc;
    }
    __syncthreads();
    for (int off = 1; off < 128; off <<= 1) {   // inclusive scan of padded counts
        unsigned v = (tid >= off && tid < 128) ? hist[tid - off] : 0;
        __syncthreads();
        if (tid < 128) hist[tid] += v;
        __syncthreads();
    }
    if (tid < 128) {
        unsigned excl = hist[tid] - pc;
        dstart[tid] = excl;
        cur[tid] = excl;
        if (tid == 127) dstart[128] = hist[127];
    }
    __syncthreads();
    for (unsigned i = tid; i < cnt; i += 256) {   // scatter into LDS sorted order
        unsigned w = bucketed[i];
        unsigned r = atomicAdd(&cur[w >> 17], 1u);
        srcsL[r] = (w & 0x1FFFFu) << 7;           // byte offset of 128B row
    }
    if (tid < 128) {
        const unsigned DUMMY = ((unsigned)(3 * N_NODES) << 7) | 1u;  // flag bit 0
        unsigned excl = dstart[tid];
        for (unsigned k = c; k < pc; ++k) srcsL[excl + k] = DUMMY;
    }
    __syncthreads();

    // ---- aggregation: 32 groups x 8 lanes; work-stealing over the 128 dsts
    const int l = tid & 7;
    const int grpBase = tid & ~7;
    const unsigned lofs = (unsigned)(l << 4);
    int c0 = 8 * l;
    h2 at[4];
    const float LOG2E = 1.4426950408889634f;
#pragma unroll
    for (int i = 0; i < 4; ++i) {
        int cc = c0 + 2 * i;
        float lo = (cc < D_OUT) ? att[cc] * LOG2E : 0.f;
        float hi = (cc + 1 < D_OUT) ? att[cc + 1] * LOG2E : 0.f;
        at[i] = h2{(_Float16)lo, (_Float16)hi};
    }
    for (;;) {
        unsigned d;
        if (l == 0) d = atomicAdd(&nextD, 1u);
        d = (unsigned)__shfl((int)d, grpBase);
        if (d >= 128u) break;
        int g = (b << 7) + (int)d;
        if (g >= N_NODES) continue;
        uint4 xru = xr4[g * 8 + l];
        h2 xr[4] = {bch2(xru.x), bch2(xru.y), bch2(xru.z), bch2(xru.w)};
        uint4 xs = *(const uint4*)(xlb + (size_t)g * 128 + lofs);

        float q = edge_score8(xs, xr, at);
        q += __shfl_xor(q, 1); q += __shfl_xor(q, 2); q += __shfl_xor(q, 4);
        float S = exp2f(q);                     // scores bounded: raw exp safe
        float2 O[4] = {{0.f, 0.f}, {0.f, 0.f}, {0.f, 0.f}, {0.f, 0.f}};
        accum8(O, S, xs);

        unsigned j = dstart[d], jE = dstart[d + 1];
        if (j < jE) {
            uint4 vv = *(const uint4*)&srcsL[j];       // ds_read_b128
            uint4 c0v = *(const uint4*)(xlb + ((vv.x & ~1u) + lofs));
            uint4 c1v = *(const uint4*)(xlb + ((vv.y & ~1u) + lofs));
            uint4 c2v = *(const uint4*)(xlb + ((vv.z & ~1u) + lofs));
            uint4 c3v = *(const uint4*)(xlb + ((vv.w & ~1u) + lofs));
            for (;;) {
                j += 4;
                bool more = j < jE;
                uint4 nv, p0v, p1v, p2v, p3v;
                if (more) {
                    nv = *(const uint4*)&srcsL[j];
                    p0v = *(const uint4*)(xlb + ((nv.x & ~1u) + lofs));
                    p1v = *(const uint4*)(xlb + ((nv.y & ~1u) + lofs));
                    p2v = *(const uint4*)(xlb + ((nv.z & ~1u) + lofs));
                    p3v = *(const uint4*)(xlb + ((nv.w & ~1u) + lofs));
                }
                float p0 = edge_score8(c0v, xr, at);
                float p1 = edge_score8(c1v, xr, at);
                float p2 = edge_score8(c2v, xr, at);
                float p3 = edge_score8(c3v, xr, at);
                p0 += __shfl_xor(p0, 1); p0 += __shfl_xor(p0, 2); p0 += __shfl_xor(p0, 4);
                p1 += __shfl_xor(p1, 1); p1 += __shfl_xor(p1, 2); p1 += __shfl_xor(p1, 4);
                p2 += __shfl_xor(p2, 1); p2 += __shfl_xor(p2, 2); p2 += __shfl_xor(p2, 4);
                p3 += __shfl_xor(p3, 1); p3 += __shfl_xor(p3, 2); p3 += __shfl_xor(p3, 4);
                float w0 = (vv.x & 1u) ? 0.f : exp2f(p0);
                float w1 = (vv.y & 1u) ? 0.f : exp2f(p1);
                float w2 = (vv.z & 1u) ? 0.f : exp2f(p2);
                float w3 = (vv.w & 1u) ? 0.f : exp2f(p3);
                S += (w0 + w1) + (w2 + w3);
                accum8(O, w0, c0v);
                accum8(O, w1, c1v);
                accum8(O, w2, c2v);
                accum8(O, w3, c3v);
                if (!more) break;
                vv = nv; c0v = p0v; c1v = p1v; c2v = p2v; c3v = p3v;
            }
        }
        float inv = 1.f / (S + 1e-16f);
        size_t base = (size_t)g * 160 + col0 + c0;
#pragma unroll
        for (int i = 0; i < 4; ++i) {
            int cc = c0 + 2 * i;
            if (cc + 1 < D_OUT) {
                float blo = bo[cc], bhi = bo[cc + 1];
                float vlo = lrelu(O[i].x * inv + blo, 0.1f);
                float vhi = lrelu(O[i].y * inv + bhi, 0.1f);
                *(__half2*)&h16[base + 2 * i] = __floats2half2_rn(vlo, vhi);
            }
        }
    }
}

// ---------------- fused MFMA MLP head, wave-independent 16-node tiles ------------
#define HS 168

template<int NOT, int NKS, bool ACT>
__device__ __forceinline__ void head_layer(
    const _Float16* __restrict__ in, _Float16* __restrict__ outp,
    const unsigned short* __restrict__ wp, const float* __restrict__ bias, int l)
{
    const int lm = l & 15, q = l >> 4;
    const _Float16* aBase = in + lm * HS + q * 8;
#pragma unroll
    for (int ot = 0; ot < NOT; ++ot) {
        float4v acc = {0.f, 0.f, 0.f, 0.f};
        const unsigned short* bBase = wp + (ot * NKS) * 512 + l * 8;
#pragma unroll
        for (int ks = 0; ks < NKS; ++ks) {
            half8 a = *(const half8*)(aBase + ks * 32);
            half8 b = *(const half8*)(bBase + ks * 512);
            acc = __builtin_amdgcn_mfma_f32_16x16x32_f16(a, b, acc, 0, 0, 0);
        }
        float bv = bias[ot * 16 + lm];
#pragma unroll
        for (int r = 0; r < 4; ++r) {
            float v = acc[r] + bv;
            if (ACT) v = lrelu(v, 0.1f);
            outp[(q * 4 + r) * HS + ot * 16 + lm] = (_Float16)v;
        }
    }
}

__global__ __launch_bounds__(256) void mfma_head_kernel(
    const __half* __restrict__ h16,
    const unsigned short* __restrict__ wpkAll, const float* __restrict__ biasPad,
    float* __restrict__ out)
{
    __shared__ _Float16 sIn[4][16 * HS];
    __shared__ _Float16 sOut[4][16 * HS];
    int tid = threadIdx.x;
    int w = tid >> 6, l = tid & 63;
    int g0 = blockIdx.x * 64 + w * 16;

    const uint2* hq = (const uint2*)h16;
    for (int idx = l; idx < 16 * 42; idx += 64) {
        int row = idx / 42, qc = idx - row * 42;
        int gn = g0 + row;
        uint2 u = {0u, 0u};
        if (gn < N_NODES && qc < 40) {
            u = hq[(size_t)gn * 40 + qc];
            if (qc == 37) u.y = 0u;
            else if (qc > 37) { u.x = 0u; u.y = 0u; }
        }
        *(uint2*)&sIn[w][row * HS + qc * 4] = u;
    }
    __syncthreads();
    head_layer<10, 5, false>(sIn[w], sOut[w], wpkAll,         biasPad + 0,   l);
    __syncthreads();
    head_layer<6, 5, true >(sOut[w], sIn[w], wpkAll + 25600,  biasPad + 160, l);
    __syncthreads();
    head_layer<2, 3, true >(sIn[w], sOut[w], wpkAll + 40960,  biasPad + 256, l);
    __syncthreads();
    {
        const int lm = l & 15, q = l >> 4;
        float4v acc = {0.f, 0.f, 0.f, 0.f};
        half8 a = *(const half8*)(sOut[w] + lm * HS + q * 8);
        half8 b = *(const half8*)(wpkAll + 44032 + l * 8);
        acc = __builtin_amdgcn_mfma_f32_16x16x32_f16(a, b, acc, 0, 0, 0);
        if (lm < 2) {
            float bv = biasPad[288 + lm];
#pragma unroll
            for (int r = 0; r < 4; ++r) {
                int node = g0 + q * 4 + r;
                if (node < N_NODES) out[node * 2 + lm] = acc[r] + bv;
            }
        }
    }
}

extern "C" void kernel_launch(void* const* d_in, const int* in_sizes, int n_in,
                              void* d_out, int out_size, void* d_ws, size_t ws_size,
                              hipStream_t stream)
{
    const float* x = (const float*)d_in[0];
    const int* eip = (const int*)d_in[1];
    const int* eis = (const int*)d_in[2];
    const int* eiv = (const int*)d_in[3];
    const float *Wl[3], *bl[3], *Wr[3], *br[3], *att[3], *bo[3];
    for (int t = 0; t < 3; ++t) {
        int b = 4 + t * 6;
        Wl[t] = (const float*)d_in[b + 0];
        bl[t] = (const float*)d_in[b + 1];
        Wr[t] = (const float*)d_in[b + 2];
        br[t] = (const float*)d_in[b + 3];
        att[t] = (const float*)d_in[b + 4];
        bo[t] = (const float*)d_in[b + 5];
    }
    const float* projW = (const float*)d_in[22];
    const float* projb = (const float*)d_in[23];
    const float* W1 = (const float*)d_in[24];
    const float* b1 = (const float*)d_in[25];
    const float* W2 = (const float*)d_in[26];
    const float* b2 = (const float*)d_in[27];
    const float* W3 = (const float*)d_in[28];
    const float* b3 = (const float*)d_in[29];
    float* out = (float*)d_out;

    char* ws = (char*)d_ws;
    size_t off = 0;
    auto alloc = [&](size_t bytes) -> char* {
        char* p = ws + off;
        off += (bytes + 255) & ~(size_t)255;
        return p;
    };
    // xl3 has one extra zero row at absolute row index 3*N_NODES (dummy target)
    __half* xl3 = (__half*)alloc(((size_t)3 * N_NODES * 64 + 64) * 2);  // 38.4 MB
    __half* xr3 = (__half*)alloc((size_t)3 * N_NODES * 64 * 2);         // 38.4 MB
    unsigned* bucketed3 = (unsigned*)alloc((size_t)3 * NBKT * BSTR * 4); // 24 MB
    unsigned* bcur3 = (unsigned*)alloc((size_t)3 * NBKT * 4);
    __half* h16 = (__half*)alloc((size_t)N_NODES * 160 * 2);            // 32 MB
    unsigned short* wpkAll = (unsigned short*)alloc(56832 * 2);
    float* biasPad = (float*)alloc(688 * 4);

    // pack (also zeroes bcur3 and the dummy row)
    pack_all_kernel<<<(57584 + 3 * NBKT + 255) / 256, 256, 0, stream>>>(
        projW, W1, W2, W3, projb, b1, b2, b3,
        Wl[0], Wr[0], Wl[1], Wr[1], Wl[2], Wr[2],
        bl[0], br[0], bl[1], br[1], bl[2], br[2],
        wpkAll, biasPad, xl3, bcur3);

    // fused scatter + transform
    prep_kernel<<<NBLK_SCAT + NBLK_TRANS, 256, 0, stream>>>(
        eip, eis, eiv, bcur3, bucketed3, x, wpkAll, biasPad, xl3, xr3);

    bkt_gat_kernel<<<dim3(NBKT, 3), 256, 0, stream>>>(
        bucketed3, bcur3, xl3, xr3,
        att[0], att[1], att[2], bo[0], bo[1], bo[2], h16);

    mfma_head_kernel<<<(N_NODES + 63) / 64, 256, 0, stream>>>(h16, wpkAll, biasPad, out);
}

// Round 11
// 415.522 us; speedup vs baseline: 1.0227x; 1.0227x over previous
//
#include <hip/hip_runtime.h>
#include <hip/hip_fp16.h>

#define N_NODES 100000
#define N_EDGES 1600000
#define D_IN 25
#define D_OUT 50
#define NBKT 782        // ceil(N_NODES/128) coarse buckets (dst>>7)
#define EPB 8192        // edges per block in scatter pass
#define NBLK_E 196      // ceil(N_EDGES/EPB)
#define BSTR 2560       // fixed bucket stride (mean 2048 + >10 sigma)
#define CAP 2944        // LDS sorted-list capacity (BSTR + 128*3 padding)

typedef __attribute__((ext_vector_type(8))) _Float16 half8;
typedef __attribute__((ext_vector_type(2))) _Float16 h2;
typedef __attribute__((ext_vector_type(4))) float float4v;

__device__ __forceinline__ float lrelu(float x, float a) { return fmaxf(x, a * x); }
__device__ __forceinline__ h2 bch2(unsigned u) { return __builtin_bit_cast(h2, u); }

// ---------------- fused bucket scatter: LDS hist -> global reserve -> write ------
__global__ __launch_bounds__(256) void bkt_scatter_kernel(
    const int* __restrict__ eip, const int* __restrict__ eis, const int* __restrict__ eiv,
    unsigned* __restrict__ bcur3, unsigned* __restrict__ bucketed3)
{
    int t = blockIdx.y;
    const int* ei = (t == 0) ? eip : ((t == 1) ? eis : eiv);
    unsigned* bcur = bcur3 + t * NBKT;
    unsigned* bucketed = bucketed3 + (size_t)t * NBKT * BSTR;
    __shared__ unsigned h[NBKT];
    __shared__ unsigned cur[NBKT];
    int tid = threadIdx.x;
    for (int b = tid; b < NBKT; b += 256) h[b] = 0;
    __syncthreads();
#pragma unroll
    for (int i = 0; i < EPB / 256; ++i) {
        int e = blockIdx.x * EPB + i * 256 + tid;
        if (e < N_EDGES) atomicAdd(&h[ei[N_EDGES + e] >> 7], 1u);
    }
    __syncthreads();
    for (int b = tid; b < NBKT; b += 256)
        cur[b] = (unsigned)b * BSTR + (h[b] ? atomicAdd(&bcur[b], h[b]) : 0u);
    __syncthreads();
#pragma unroll
    for (int i = 0; i < EPB / 256; ++i) {
        int e = blockIdx.x * EPB + i * 256 + tid;
        if (e < N_EDGES) {
            unsigned s = (unsigned)ei[e];
            unsigned d = (unsigned)ei[N_EDGES + e];
            unsigned b = d >> 7;
            unsigned r = atomicAdd(&cur[b], 1u);
            if (r < (b + 1u) * BSTR)           // overflow guard (>10-sigma margin)
                bucketed[r] = ((d & 127u) << 17) | s;
        }
    }
}

// ---------------- pack: head B-fragments (fp16) + transform weights + biases -----
// wpkAll: [0:25600) proj  [25600:40960) cls1  [40960:44032) cls2  [44032:44544) cls3
//         [44544:56832) transform 6 mats x 4 chunks x 512
// biasPad: [0:304) head; [304:688) transform 6 x 64
__device__ __forceinline__ void pack_seg(
    const float* __restrict__ W, unsigned short* __restrict__ outp,
    int K, int O, int NKS, int idx)
{
    int f = idx >> 9, r = idx & 511;
    int l = r >> 3, j = r & 7;
    int ot = f / NKS, ks = f - ot * NKS;
    int k = ks * 32 + (l >> 4) * 8 + j;
    int o = ot * 16 + (l & 15);
    float val = (k < K && o < O) ? W[k * O + o] : 0.f;
    outp[idx] = __half_as_ushort(__float2half_rn(val));
}

__global__ __launch_bounds__(256) void pack_all_kernel(
    const float* __restrict__ projW, const float* __restrict__ W1,
    const float* __restrict__ W2, const float* __restrict__ W3,
    const float* __restrict__ b0, const float* __restrict__ b1,
    const float* __restrict__ b2, const float* __restrict__ b3,
    const float* __restrict__ Wl0, const float* __restrict__ Wr0,
    const float* __restrict__ Wl1, const float* __restrict__ Wr1,
    const float* __restrict__ Wl2, const float* __restrict__ Wr2,
    const float* __restrict__ bl0, const float* __restrict__ br0,
    const float* __restrict__ bl1, const float* __restrict__ br1,
    const float* __restrict__ bl2, const float* __restrict__ br2,
    unsigned short* __restrict__ wpkAll, float* __restrict__ biasPad,
    __half* __restrict__ xl3)
{
    int gid = blockIdx.x * 256 + threadIdx.x;
    if (gid < 25600) pack_seg(projW, wpkAll, 150, 150, 5, gid);
    else if (gid < 40960) pack_seg(W1, wpkAll + 25600, 150, 75, 5, gid - 25600);
    else if (gid < 44032) pack_seg(W2, wpkAll + 40960, 75, 30, 3, gid - 40960);
    else if (gid < 44544) pack_seg(W3, wpkAll + 44032, 30, 2, 1, gid - 44032);
    else if (gid < 56832) {
        int t = gid - 44544;
        int mat = t >> 11, idx = t & 2047;
        const float* Wm = (mat == 0) ? Wl0 : (mat == 1) ? Wr0 : (mat == 2) ? Wl1
                        : (mat == 3) ? Wr1 : (mat == 4) ? Wl2 : Wr2;
        int ot = idx >> 9, r = idx & 511;
        int l = r >> 3, j = r & 7;
        int k = (l >> 4) * 8 + j;
        int o = ot * 16 + (l & 15);
        float val = (k < D_IN && o < D_OUT) ? Wm[k * D_OUT + o] : 0.f;
        wpkAll[44544 + t] = __half_as_ushort(__float2half_rn(val));
    } else if (gid < 57520) {
        int t = gid - 56832;
        float v;
        if (t < 304) {
            if (t < 160) v = (t < 150) ? b0[t] : 0.f;
            else if (t < 256) { int i = t - 160; v = (i < 75) ? b1[i] : 0.f; }
            else if (t < 288) { int i = t - 256; v = (i < 30) ? b2[i] : 0.f; }
            else { int i = t - 288; v = (i < 2) ? b3[i] : 0.f; }
        } else {
            int ii = t - 304;
            int mat = ii >> 6, o = ii & 63;
            const float* bm = (mat == 0) ? bl0 : (mat == 1) ? br0 : (mat == 2) ? bl1
                            : (mat == 3) ? br1 : (mat == 4) ? bl2 : br2;
            v = (o < D_OUT) ? bm[o] : 0.f;
        }
        biasPad[t] = v;
    } else if (gid < 57584) {
        // zero row at absolute row 3*N_NODES: dummy-edge gather target
        xl3[(size_t)3 * N_NODES * 64 + (gid - 57520)] = __ushort_as_half((unsigned short)0);
    }
}

// ---------------- MFMA node transform: xl/xr (6 mats) via 16x16x32 f16 -----------
#define TSTR 32
#define OSTR 72

__global__ __launch_bounds__(256) void transform_mfma_kernel(
    const float* __restrict__ x,
    const unsigned short* __restrict__ wpkAll, const float* __restrict__ biasPad,
    __half* __restrict__ xl3, __half* __restrict__ xr3)
{
    __shared__ _Float16 sX[64 * TSTR];
    __shared__ _Float16 sO[4][16 * OSTR];
    int tid = threadIdx.x;
    int w = tid >> 6, l = tid & 63;
    int g0 = blockIdx.x * 64;
    for (int i = tid; i < 64 * D_IN; i += 256) {
        int r = i / D_IN, c = i - r * D_IN;
        int gr = g0 + r;
        sX[r * TSTR + c] = (gr < N_NODES) ? (_Float16)x[(size_t)gr * D_IN + c] : (_Float16)0.f;
    }
    for (int i = tid; i < 64 * 7; i += 256) {
        int r = i / 7, c = D_IN + (i - r * 7);
        sX[r * TSTR + c] = (_Float16)0.f;
    }
    __syncthreads();
    int lm = l & 15, q = l >> 4;
    half8 a = *(const half8*)(sX + (w * 16 + lm) * TSTR + q * 8);
    const unsigned short* wT = wpkAll + 44544;
#pragma unroll
    for (int mat = 0; mat < 6; ++mat) {
        float4v acc[4];
#pragma unroll
        for (int ot = 0; ot < 4; ++ot) {
            half8 b = *(const half8*)(wT + (mat * 4 + ot) * 512 + l * 8);
            float4v z = {0.f, 0.f, 0.f, 0.f};
            acc[ot] = __builtin_amdgcn_mfma_f32_16x16x32_f16(a, b, z, 0, 0, 0);
        }
#pragma unroll
        for (int ot = 0; ot < 4; ++ot) {
            float bv = biasPad[304 + mat * 64 + ot * 16 + lm];
#pragma unroll
            for (int r = 0; r < 4; ++r)
                sO[w][(q * 4 + r) * OSTR + ot * 16 + lm] = (_Float16)(acc[ot][r] + bv);
        }
        __half* dst = ((mat & 1) ? xr3 : xl3) + (size_t)(mat >> 1) * N_NODES * 64;
#pragma unroll
        for (int it = 0; it < 2; ++it) {
            int idx = it * 64 + l;
            int rr = idx >> 3, cc = idx & 7;
            int gr = g0 + w * 16 + rr;
            if (gr < N_NODES) {
                uint4 v = *(const uint4*)&sO[w][rr * OSTR + cc * 8];
                *(uint4*)&dst[(size_t)gr * 64 + cc * 8] = v;
            }
        }
    }
}

// ---------------- fused fine-sort + GATv2 aggregation ----------------------------
// One block per (bucket of 128 dsts, tag): LDS hist+scan+scatter (padded to x4
// with flagged dummy zero-row entries), then 8-lane-group aggregation with LDS
// work-stealing over the bucket's dsts. att pre-scaled by log2(e): exp2 weights.
__device__ __forceinline__ float edge_score8(uint4 u, const h2* xr, const h2* at)
{
    const h2 k2 = {(_Float16)0.2f, (_Float16)0.2f};
    float acc = 0.f;
    unsigned uu[4] = {u.x, u.y, u.z, u.w};
#pragma unroll
    for (int i = 0; i < 4; ++i) {
        h2 m = bch2(uu[i]) + xr[i];
        m = __builtin_elementwise_max(m, m * k2);
        acc = __builtin_amdgcn_fdot2(m, at[i], acc, false);
    }
    return acc;
}
__device__ __forceinline__ void accum8(float2* O, float w, uint4 u)
{
    unsigned uu[4] = {u.x, u.y, u.z, u.w};
#pragma unroll
    for (int i = 0; i < 4; ++i) {
        h2 xv = bch2(uu[i]);
        O[i].x += w * (float)xv[0];
        O[i].y += w * (float)xv[1];
    }
}

__global__ __launch_bounds__(256) void bkt_gat_kernel(
    const unsigned* __restrict__ bucketed3, const unsigned* __restrict__ bcur3,
    const __half* __restrict__ xl3, const __half* __restrict__ xr3,
    const float* __restrict__ att0, const float* __restrict__ att1, const float* __restrict__ att2,
    const float* __restrict__ bo0, const float* __restrict__ bo1, const float* __restrict__ bo2,
    __half* __restrict__ h16)
{
    int tag = blockIdx.y, b = blockIdx.x;
    const unsigned* bucketed = bucketed3 + (size_t)tag * NBKT * BSTR + (size_t)b * BSTR;
    const uint4* xl4 = (const uint4*)xl3 + (size_t)tag * N_NODES * 8;
    const uint4* xr4 = (const uint4*)xr3 + (size_t)tag * N_NODES * 8;
    const float* att = (tag == 0) ? att0 : (tag == 1) ? att1 : att2;
    const float* bo  = (tag == 0) ? bo0  : (tag == 1) ? bo1  : bo2;
    int col0 = tag * 50;

    __shared__ unsigned hist[128];
    __shared__ unsigned dstart[129];
    __shared__ unsigned cur[128];
    __shared__ unsigned srcsL[CAP];
    __shared__ unsigned nextD;
    int tid = threadIdx.x;
    unsigned cnt = bcur3[tag * NBKT + b];
    if (cnt > BSTR) cnt = BSTR;
    if (tid < 128) hist[tid] = 0;
    if (tid == 0) nextD = 0;
    __syncthreads();
    for (unsigned i = tid; i < cnt; i += 256) atomicAdd(&hist[bucketed[i] >> 17], 1u);
    __syncthreads();
    unsigned c = 0, pc = 0;
    if (tid < 128) {
        c = hist[tid];
        pc = (c + 3u) & ~3u;          // pad each dst's list to multiple of 4
        hist[tid] = pc;
    }
    __syncthreads();
    for (int off = 1; off < 128; off <<= 1) {   // inclusive scan of padded counts
        unsigned v = (tid >= off && tid < 128) ? hist[tid - off] : 0;
        __syncthreads();
        if (tid < 128) hist[tid] += v;
        __syncthreads();
    }
    if (tid < 128) {
        unsigned excl = hist[tid] - pc;
        dstart[tid] = excl;
        cur[tid] = excl;
        if (tid == 127) dstart[128] = hist[127];
    }
    __syncthreads();
    for (unsigned i = tid; i < cnt; i += 256) {   // scatter into LDS sorted order
        unsigned w = bucketed[i];
        unsigned r = atomicAdd(&cur[w >> 17], 1u);
        srcsL[r] = (w & 0x1FFFFu) << 3;           // pre-scaled uint4 row index
    }
    if (tid < 128) {
        const unsigned DUMMY = 0x80000000u | ((unsigned)(3 * N_NODES) << 3);
        unsigned excl = dstart[tid];
        for (unsigned k = c; k < pc; ++k) srcsL[excl + k] = DUMMY;  // disjoint slots
    }
    __syncthreads();

    // ---- aggregation: 32 groups x 8 lanes; work-stealing over the 128 dsts
    const int l = tid & 7;
    const int grpBase = tid & ~7;
    int c0 = 8 * l;
    h2 at[4];
    const float LOG2E = 1.4426950408889634f;
#pragma unroll
    for (int i = 0; i < 4; ++i) {
        int cc = c0 + 2 * i;
        float lo = (cc < D_OUT) ? att[cc] * LOG2E : 0.f;
        float hi = (cc + 1 < D_OUT) ? att[cc + 1] * LOG2E : 0.f;
        at[i] = h2{(_Float16)lo, (_Float16)hi};
    }
    for (;;) {
        unsigned d;
        if (l == 0) d = atomicAdd(&nextD, 1u);
        d = (unsigned)__shfl((int)d, grpBase);
        if (d >= 128u) break;
        int g = (b << 7) + (int)d;
        if (g >= N_NODES) continue;
        uint4 xru = xr4[g * 8 + l];
        h2 xr[4] = {bch2(xru.x), bch2(xru.y), bch2(xru.z), bch2(xru.w)};
        uint4 xs = xl4[g * 8 + l];

        float q = edge_score8(xs, xr, at);
        q += __shfl_xor(q, 1); q += __shfl_xor(q, 2); q += __shfl_xor(q, 4);
        float S = exp2f(q);                     // scores bounded: raw exp safe
        float2 O[4] = {{0.f, 0.f}, {0.f, 0.f}, {0.f, 0.f}, {0.f, 0.f}};
        accum8(O, S, xs);

        unsigned j = dstart[d], jE = dstart[d + 1];
        if (j < jE) {
            uint4 vv = *(const uint4*)&srcsL[j];       // ds_read_b128, 16B-aligned
            uint4 c0v = xl4[(vv.x & 0x7FFFFFFFu) + l];
            uint4 c1v = xl4[(vv.y & 0x7FFFFFFFu) + l];
            uint4 c2v = xl4[(vv.z & 0x7FFFFFFFu) + l];
            uint4 c3v = xl4[(vv.w & 0x7FFFFFFFu) + l];
            for (;;) {
                j += 4;
                bool more = j < jE;
                uint4 nv, p0v, p1v, p2v, p3v;
                if (more) {
                    nv = *(const uint4*)&srcsL[j];
                    p0v = xl4[(nv.x & 0x7FFFFFFFu) + l];
                    p1v = xl4[(nv.y & 0x7FFFFFFFu) + l];
                    p2v = xl4[(nv.z & 0x7FFFFFFFu) + l];
                    p3v = xl4[(nv.w & 0x7FFFFFFFu) + l];
                }
                float p0 = edge_score8(c0v, xr, at);
                float p1 = edge_score8(c1v, xr, at);
                float p2 = edge_score8(c2v, xr, at);
                float p3 = edge_score8(c3v, xr, at);
                p0 += __shfl_xor(p0, 1); p0 += __shfl_xor(p0, 2); p0 += __shfl_xor(p0, 4);
                p1 += __shfl_xor(p1, 1); p1 += __shfl_xor(p1, 2); p1 += __shfl_xor(p1, 4);
                p2 += __shfl_xor(p2, 1); p2 += __shfl_xor(p2, 2); p2 += __shfl_xor(p2, 4);
                p3 += __shfl_xor(p3, 1); p3 += __shfl_xor(p3, 2); p3 += __shfl_xor(p3, 4);
                float w0 = (vv.x & 0x80000000u) ? 0.f : exp2f(p0);
                float w1 = (vv.y & 0x80000000u) ? 0.f : exp2f(p1);
                float w2 = (vv.z & 0x80000000u) ? 0.f : exp2f(p2);
                float w3 = (vv.w & 0x80000000u) ? 0.f : exp2f(p3);
                S += (w0 + w1) + (w2 + w3);
                accum8(O, w0, c0v);
                accum8(O, w1, c1v);
                accum8(O, w2, c2v);
                accum8(O, w3, c3v);
                if (!more) break;
                vv = nv; c0v = p0v; c1v = p1v; c2v = p2v; c3v = p3v;
            }
        }
        float inv = 1.f / (S + 1e-16f);
        size_t base = (size_t)g * 160 + col0 + c0;
#pragma unroll
        for (int i = 0; i < 4; ++i) {
            int cc = c0 + 2 * i;
            if (cc + 1 < D_OUT) {
                float blo = bo[cc], bhi = bo[cc + 1];
                float vlo = lrelu(O[i].x * inv + blo, 0.1f);
                float vhi = lrelu(O[i].y * inv + bhi, 0.1f);
                *(__half2*)&h16[base + 2 * i] = __floats2half2_rn(vlo, vhi);
            }
        }
    }
}

// ---------------- fused MFMA MLP head, wave-independent 16-node tiles ------------
#define HS 168

template<int NOT, int NKS, bool ACT>
__device__ __forceinline__ void head_layer(
    const _Float16* __restrict__ in, _Float16* __restrict__ outp,
    const unsigned short* __restrict__ wp, const float* __restrict__ bias, int l)
{
    const int lm = l & 15, q = l >> 4;
    const _Float16* aBase = in + lm * HS + q * 8;
#pragma unroll
    for (int ot = 0; ot < NOT; ++ot) {
        float4v acc = {0.f, 0.f, 0.f, 0.f};
        const unsigned short* bBase = wp + (ot * NKS) * 512 + l * 8;
#pragma unroll
        for (int ks = 0; ks < NKS; ++ks) {
            half8 a = *(const half8*)(aBase + ks * 32);
            half8 b = *(const half8*)(bBase + ks * 512);
            acc = __builtin_amdgcn_mfma_f32_16x16x32_f16(a, b, acc, 0, 0, 0);
        }
        float bv = bias[ot * 16 + lm];
#pragma unroll
        for (int r = 0; r < 4; ++r) {
            float v = acc[r] + bv;
            if (ACT) v = lrelu(v, 0.1f);
            outp[(q * 4 + r) * HS + ot * 16 + lm] = (_Float16)v;
        }
    }
}

__global__ __launch_bounds__(256) void mfma_head_kernel(
    const __half* __restrict__ h16,
    const unsigned short* __restrict__ wpkAll, const float* __restrict__ biasPad,
    float* __restrict__ out)
{
    __shared__ _Float16 sIn[4][16 * HS];
    __shared__ _Float16 sOut[4][16 * HS];
    int tid = threadIdx.x;
    int w = tid >> 6, l = tid & 63;
    int g0 = blockIdx.x * 64 + w * 16;

    const uint2* hq = (const uint2*)h16;
    for (int idx = l; idx < 16 * 42; idx += 64) {
        int row = idx / 42, qc = idx - row * 42;
        int gn = g0 + row;
        uint2 u = {0u, 0u};
        if (gn < N_NODES && qc < 40) {
            u = hq[(size_t)gn * 40 + qc];
            if (qc == 37) u.y = 0u;
            else if (qc > 37) { u.x = 0u; u.y = 0u; }
        }
        *(uint2*)&sIn[w][row * HS + qc * 4] = u;
    }
    __syncthreads();
    head_layer<10, 5, false>(sIn[w], sOut[w], wpkAll,         biasPad + 0,   l);
    __syncthreads();
    head_layer<6, 5, true >(sOut[w], sIn[w], wpkAll + 25600,  biasPad + 160, l);
    __syncthreads();
    head_layer<2, 3, true >(sIn[w], sOut[w], wpkAll + 40960,  biasPad + 256, l);
    __syncthreads();
    {
        const int lm = l & 15, q = l >> 4;
        float4v acc = {0.f, 0.f, 0.f, 0.f};
        half8 a = *(const half8*)(sOut[w] + lm * HS + q * 8);
        half8 b = *(const half8*)(wpkAll + 44032 + l * 8);
        acc = __builtin_amdgcn_mfma_f32_16x16x32_f16(a, b, acc, 0, 0, 0);
        if (lm < 2) {
            float bv = biasPad[288 + lm];
#pragma unroll
            for (int r = 0; r < 4; ++r) {
                int node = g0 + q * 4 + r;
                if (node < N_NODES) out[node * 2 + lm] = acc[r] + bv;
            }
        }
    }
}

extern "C" void kernel_launch(void* const* d_in, const int* in_sizes, int n_in,
                              void* d_out, int out_size, void* d_ws, size_t ws_size,
                              hipStream_t stream)
{
    const float* x = (const float*)d_in[0];
    const int* eip = (const int*)d_in[1];
    const int* eis = (const int*)d_in[2];
    const int* eiv = (const int*)d_in[3];
    const float *Wl[3], *bl[3], *Wr[3], *br[3], *att[3], *bo[3];
    for (int t = 0; t < 3; ++t) {
        int b = 4 + t * 6;
        Wl[t] = (const float*)d_in[b + 0];
        bl[t] = (const float*)d_in[b + 1];
        Wr[t] = (const float*)d_in[b + 2];
        br[t] = (const float*)d_in[b + 3];
        att[t] = (const float*)d_in[b + 4];
        bo[t] = (const float*)d_in[b + 5];
    }
    const float* projW = (const float*)d_in[22];
    const float* projb = (const float*)d_in[23];
    const float* W1 = (const float*)d_in[24];
    const float* b1 = (const float*)d_in[25];
    const float* W2 = (const float*)d_in[26];
    const float* b2 = (const float*)d_in[27];
    const float* W3 = (const float*)d_in[28];
    const float* b3 = (const float*)d_in[29];
    float* out = (float*)d_out;

    char* ws = (char*)d_ws;
    size_t off = 0;
    auto alloc = [&](size_t bytes) -> char* {
        char* p = ws + off;
        off += (bytes + 255) & ~(size_t)255;
        return p;
    };
    // xl3 has one extra zero row at absolute row index 3*N_NODES (dummy target)
    __half* xl3 = (__half*)alloc(((size_t)3 * N_NODES * 64 + 64) * 2);  // 38.4 MB
    __half* xr3 = (__half*)alloc((size_t)3 * N_NODES * 64 * 2);         // 38.4 MB
    unsigned* bucketed3 = (unsigned*)alloc((size_t)3 * NBKT * BSTR * 4); // 24 MB
    unsigned* bcur3 = (unsigned*)alloc((size_t)3 * NBKT * 4);
    __half* h16 = (__half*)alloc((size_t)N_NODES * 160 * 2);            // 32 MB
    unsigned short* wpkAll = (unsigned short*)alloc(56832 * 2);
    float* biasPad = (float*)alloc(688 * 4);

    hipMemsetAsync(bcur3, 0, (size_t)3 * NBKT * 4, stream);
    pack_all_kernel<<<226, 256, 0, stream>>>(
        projW, W1, W2, W3, projb, b1, b2, b3,
        Wl[0], Wr[0], Wl[1], Wr[1], Wl[2], Wr[2],
        bl[0], br[0], bl[1], br[1], bl[2], br[2],
        wpkAll, biasPad, xl3);

    bkt_scatter_kernel<<<dim3(NBLK_E, 3), 256, 0, stream>>>(eip, eis, eiv, bcur3, bucketed3);

    transform_mfma_kernel<<<(N_NODES + 63) / 64, 256, 0, stream>>>(
        x, wpkAll, biasPad, xl3, xr3);

    bkt_gat_kernel<<<dim3(NBKT, 3), 256, 0, stream>>>(
        bucketed3, bcur3, xl3, xr3,
        att[0], att[1], att[2], bo[0], bo[1], bo[2], h16);

    mfma_head_kernel<<<(N_NODES + 63) / 64, 256, 0, stream>>>(h16, wpkAll, biasPad, out);
}

// Round 13
// 409.500 us; speedup vs baseline: 1.0377x; 1.0147x over previous
//
#include <hip/hip_runtime.h>
#include <hip/hip_fp16.h>

#define N_NODES 100000
#define N_EDGES 1600000
#define D_IN 25
#define D_OUT 50
#define NBKT 782        // ceil(N_NODES/128) coarse buckets (dst>>7)
#define EPB 8192        // edges per block in scatter pass
#define NBLK_E 196      // ceil(N_EDGES/EPB)
#define BSTR 2560       // fixed bucket stride (mean 2048 + >10 sigma)
#define CAP 2944        // LDS sorted-list capacity (BSTR + 128*3 padding)

typedef __attribute__((ext_vector_type(8))) _Float16 half8;
typedef __attribute__((ext_vector_type(2))) _Float16 h2;
typedef __attribute__((ext_vector_type(4))) float float4v;

__device__ __forceinline__ float lrelu(float x, float a) { return fmaxf(x, a * x); }
__device__ __forceinline__ h2 bch2(unsigned u) { return __builtin_bit_cast(h2, u); }
// bare v_exp_f32: computes 2^x, no libm edge-case preamble
__device__ __forceinline__ float fexp2(float x) { return __builtin_amdgcn_exp2f(x); }

// ---------------- fused bucket scatter: LDS hist -> global reserve -> write ------
__global__ __launch_bounds__(256) void bkt_scatter_kernel(
    const int* __restrict__ eip, const int* __restrict__ eis, const int* __restrict__ eiv,
    unsigned* __restrict__ bcur3, unsigned* __restrict__ bucketed3)
{
    int t = blockIdx.y;
    const int* ei = (t == 0) ? eip : ((t == 1) ? eis : eiv);
    unsigned* bcur = bcur3 + t * NBKT;
    unsigned* bucketed = bucketed3 + (size_t)t * NBKT * BSTR;
    __shared__ unsigned h[NBKT];
    __shared__ unsigned cur[NBKT];
    int tid = threadIdx.x;
    for (int b = tid; b < NBKT; b += 256) h[b] = 0;
    __syncthreads();
#pragma unroll
    for (int i = 0; i < EPB / 256; ++i) {
        int e = blockIdx.x * EPB + i * 256 + tid;
        if (e < N_EDGES) atomicAdd(&h[ei[N_EDGES + e] >> 7], 1u);
    }
    __syncthreads();
    for (int b = tid; b < NBKT; b += 256)
        cur[b] = (unsigned)b * BSTR + (h[b] ? atomicAdd(&bcur[b], h[b]) : 0u);
    __syncthreads();
#pragma unroll
    for (int i = 0; i < EPB / 256; ++i) {
        int e = blockIdx.x * EPB + i * 256 + tid;
        if (e < N_EDGES) {
            unsigned s = (unsigned)ei[e];
            unsigned d = (unsigned)ei[N_EDGES + e];
            unsigned b = d >> 7;
            unsigned r = atomicAdd(&cur[b], 1u);
            if (r < (b + 1u) * BSTR)           // overflow guard (>10-sigma margin)
                bucketed[r] = ((d & 127u) << 17) | s;
        }
    }
}

// ---------------- pack: head B-fragments (fp16) + transform weights + biases -----
// wpkAll: [0:25600) proj  [25600:40960) cls1  [40960:44032) cls2  [44032:44544) cls3
//         [44544:56832) transform 6 mats x 4 chunks x 512
// biasPad: [0:304) head; [304:688) transform 6 x 64
__device__ __forceinline__ void pack_seg(
    const float* __restrict__ W, unsigned short* __restrict__ outp,
    int K, int O, int NKS, int idx)
{
    int f = idx >> 9, r = idx & 511;
    int l = r >> 3, j = r & 7;
    int ot = f / NKS, ks = f - ot * NKS;
    int k = ks * 32 + (l >> 4) * 8 + j;
    int o = ot * 16 + (l & 15);
    float val = (k < K && o < O) ? W[k * O + o] : 0.f;
    outp[idx] = __half_as_ushort(__float2half_rn(val));
}

__global__ __launch_bounds__(256) void pack_all_kernel(
    const float* __restrict__ projW, const float* __restrict__ W1,
    const float* __restrict__ W2, const float* __restrict__ W3,
    const float* __restrict__ b0, const float* __restrict__ b1,
    const float* __restrict__ b2, const float* __restrict__ b3,
    const float* __restrict__ Wl0, const float* __restrict__ Wr0,
    const float* __restrict__ Wl1, const float* __restrict__ Wr1,
    const float* __restrict__ Wl2, const float* __restrict__ Wr2,
    const float* __restrict__ bl0, const float* __restrict__ br0,
    const float* __restrict__ bl1, const float* __restrict__ br1,
    const float* __restrict__ bl2, const float* __restrict__ br2,
    unsigned short* __restrict__ wpkAll, float* __restrict__ biasPad,
    __half* __restrict__ xl3)
{
    int gid = blockIdx.x * 256 + threadIdx.x;
    if (gid < 25600) pack_seg(projW, wpkAll, 150, 150, 5, gid);
    else if (gid < 40960) pack_seg(W1, wpkAll + 25600, 150, 75, 5, gid - 25600);
    else if (gid < 44032) pack_seg(W2, wpkAll + 40960, 75, 30, 3, gid - 40960);
    else if (gid < 44544) pack_seg(W3, wpkAll + 44032, 30, 2, 1, gid - 44032);
    else if (gid < 56832) {
        int t = gid - 44544;
        int mat = t >> 11, idx = t & 2047;
        const float* Wm = (mat == 0) ? Wl0 : (mat == 1) ? Wr0 : (mat == 2) ? Wl1
                        : (mat == 3) ? Wr1 : (mat == 4) ? Wl2 : Wr2;
        int ot = idx >> 9, r = idx & 511;
        int l = r >> 3, j = r & 7;
        int k = (l >> 4) * 8 + j;
        int o = ot * 16 + (l & 15);
        float val = (k < D_IN && o < D_OUT) ? Wm[k * D_OUT + o] : 0.f;
        wpkAll[44544 + t] = __half_as_ushort(__float2half_rn(val));
    } else if (gid < 57520) {
        int t = gid - 56832;
        float v;
        if (t < 304) {
            if (t < 160) v = (t < 150) ? b0[t] : 0.f;
            else if (t < 256) { int i = t - 160; v = (i < 75) ? b1[i] : 0.f; }
            else if (t < 288) { int i = t - 256; v = (i < 30) ? b2[i] : 0.f; }
            else { int i = t - 288; v = (i < 2) ? b3[i] : 0.f; }
        } else {
            int ii = t - 304;
            int mat = ii >> 6, o = ii & 63;
            const float* bm = (mat == 0) ? bl0 : (mat == 1) ? br0 : (mat == 2) ? bl1
                            : (mat == 3) ? br1 : (mat == 4) ? bl2 : br2;
            v = (o < D_OUT) ? bm[o] : 0.f;
        }
        biasPad[t] = v;
    } else if (gid < 57584) {
        // zero row at absolute row 3*N_NODES: dummy-edge gather target
        xl3[(size_t)3 * N_NODES * 64 + (gid - 57520)] = __ushort_as_half((unsigned short)0);
    }
}

// ---------------- MFMA node transform: xl/xr (6 mats) via 16x16x32 f16 -----------
#define TSTR 32
#define OSTR 72

__global__ __launch_bounds__(256) void transform_mfma_kernel(
    const float* __restrict__ x,
    const unsigned short* __restrict__ wpkAll, const float* __restrict__ biasPad,
    __half* __restrict__ xl3, __half* __restrict__ xr3)
{
    __shared__ _Float16 sX[64 * TSTR];
    __shared__ _Float16 sO[4][16 * OSTR];
    int tid = threadIdx.x;
    int w = tid >> 6, l = tid & 63;
    int g0 = blockIdx.x * 64;
    for (int i = tid; i < 64 * D_IN; i += 256) {
        int r = i / D_IN, c = i - r * D_IN;
        int gr = g0 + r;
        sX[r * TSTR + c] = (gr < N_NODES) ? (_Float16)x[(size_t)gr * D_IN + c] : (_Float16)0.f;
    }
    for (int i = tid; i < 64 * 7; i += 256) {
        int r = i / 7, c = D_IN + (i - r * 7);
        sX[r * TSTR + c] = (_Float16)0.f;
    }
    __syncthreads();
    int lm = l & 15, q = l >> 4;
    half8 a = *(const half8*)(sX + (w * 16 + lm) * TSTR + q * 8);
    const unsigned short* wT = wpkAll + 44544;
#pragma unroll
    for (int mat = 0; mat < 6; ++mat) {
        float4v acc[4];
#pragma unroll
        for (int ot = 0; ot < 4; ++ot) {
            half8 b = *(const half8*)(wT + (mat * 4 + ot) * 512 + l * 8);
            float4v z = {0.f, 0.f, 0.f, 0.f};
            acc[ot] = __builtin_amdgcn_mfma_f32_16x16x32_f16(a, b, z, 0, 0, 0);
        }
#pragma unroll
        for (int ot = 0; ot < 4; ++ot) {
            float bv = biasPad[304 + mat * 64 + ot * 16 + lm];
#pragma unroll
            for (int r = 0; r < 4; ++r)
                sO[w][(q * 4 + r) * OSTR + ot * 16 + lm] = (_Float16)(acc[ot][r] + bv);
        }
        __half* dst = ((mat & 1) ? xr3 : xl3) + (size_t)(mat >> 1) * N_NODES * 64;
#pragma unroll
        for (int it = 0; it < 2; ++it) {
            int idx = it * 64 + l;
            int rr = idx >> 3, cc = idx & 7;
            int gr = g0 + w * 16 + rr;
            if (gr < N_NODES) {
                uint4 v = *(const uint4*)&sO[w][rr * OSTR + cc * 8];
                *(uint4*)&dst[(size_t)gr * 64 + cc * 8] = v;
            }
        }
    }
}

// ---------------- fused fine-sort + GATv2 aggregation ----------------------------
// One block per (bucket of 128 dsts, tag): LDS hist+scan+scatter (padded to x4
// with flagged dummy zero-row entries), then 8-lane-group aggregation with LDS
// work-stealing. att pre-scaled by log2(e); weights via bare v_exp_f32.
__device__ __forceinline__ float edge_score8(uint4 u, const h2* xr, const h2* at)
{
    const h2 k2 = {(_Float16)0.2f, (_Float16)0.2f};
    float acc = 0.f;
    unsigned uu[4] = {u.x, u.y, u.z, u.w};
#pragma unroll
    for (int i = 0; i < 4; ++i) {
        h2 m = bch2(uu[i]) + xr[i];
        m = __builtin_elementwise_max(m, m * k2);
        acc = __builtin_amdgcn_fdot2(m, at[i], acc, false);
    }
    return acc;
}
__device__ __forceinline__ void accum8(float2* O, float w, uint4 u)
{
    unsigned uu[4] = {u.x, u.y, u.z, u.w};
#pragma unroll
    for (int i = 0; i < 4; ++i) {
        h2 xv = bch2(uu[i]);
        O[i].x += w * (float)xv[0];
        O[i].y += w * (float)xv[1];
    }
}

__global__ __launch_bounds__(256) void bkt_gat_kernel(
    const unsigned* __restrict__ bucketed3, const unsigned* __restrict__ bcur3,
    const __half* __restrict__ xl3, const __half* __restrict__ xr3,
    const float* __restrict__ att0, const float* __restrict__ att1, const float* __restrict__ att2,
    const float* __restrict__ bo0, const float* __restrict__ bo1, const float* __restrict__ bo2,
    __half* __restrict__ h16)
{
    int tag = blockIdx.y, b = blockIdx.x;
    const unsigned* bucketed = bucketed3 + (size_t)tag * NBKT * BSTR + (size_t)b * BSTR;
    const uint4* xl4 = (const uint4*)xl3 + (size_t)tag * N_NODES * 8;
    const uint4* xr4 = (const uint4*)xr3 + (size_t)tag * N_NODES * 8;
    const float* att = (tag == 0) ? att0 : (tag == 1) ? att1 : att2;
    const float* bo  = (tag == 0) ? bo0  : (tag == 1) ? bo1  : bo2;
    int col0 = tag * 50;

    __shared__ unsigned hist[128];
    __shared__ unsigned dstart[129];
    __shared__ unsigned cur[128];
    __shared__ unsigned srcsL[CAP];
    __shared__ unsigned nextD;
    int tid = threadIdx.x;
    unsigned cnt = bcur3[tag * NBKT + b];
    if (cnt > BSTR) cnt = BSTR;
    if (tid < 128) hist[tid] = 0;
    if (tid == 0) nextD = 0;
    __syncthreads();
    for (unsigned i = tid; i < cnt; i += 256) atomicAdd(&hist[bucketed[i] >> 17], 1u);
    __syncthreads();
    unsigned c = 0, pc = 0;
    if (tid < 128) {
        c = hist[tid];
        pc = (c + 3u) & ~3u;          // pad each dst's list to multiple of 4
        hist[tid] = pc;
    }
    __syncthreads();
    for (int off = 1; off < 128; off <<= 1) {   // inclusive scan of padded counts
        unsigned v = (tid >= off && tid < 128) ? hist[tid - off] : 0;
        __syncthreads();
        if (tid < 128) hist[tid] += v;
        __syncthreads();
    }
    if (tid < 128) {
        unsigned excl = hist[tid] - pc;
        dstart[tid] = excl;
        cur[tid] = excl;
        if (tid == 127) dstart[128] = hist[127];
    }
    __syncthreads();
    for (unsigned i = tid; i < cnt; i += 256) {   // scatter into LDS sorted order
        unsigned w = bucketed[i];
        unsigned r = atomicAdd(&cur[w >> 17], 1u);
        srcsL[r] = (w & 0x1FFFFu) << 3;           // pre-scaled uint4 row index
    }
    if (tid < 128) {
        const unsigned DUMMY = 0x80000000u | ((unsigned)(3 * N_NODES) << 3);
        unsigned excl = dstart[tid];
        for (unsigned k = c; k < pc; ++k) srcsL[excl + k] = DUMMY;  // disjoint slots
    }
    __syncthreads();

    // ---- aggregation: 32 groups x 8 lanes; work-stealing over the 128 dsts
    const int l = tid & 7;
    const int grpBase = tid & ~7;
    int c0 = 8 * l;
    h2 at[4];
    const float LOG2E = 1.4426950408889634f;
#pragma unroll
    for (int i = 0; i < 4; ++i) {
        int cc = c0 + 2 * i;
        float lo = (cc < D_OUT) ? att[cc] * LOG2E : 0.f;
        float hi = (cc + 1 < D_OUT) ? att[cc + 1] * LOG2E : 0.f;
        at[i] = h2{(_Float16)lo, (_Float16)hi};
    }
    for (;;) {
        unsigned d;
        if (l == 0) d = atomicAdd(&nextD, 1u);
        d = (unsigned)__shfl((int)d, grpBase);
        if (d >= 128u) break;
        int g = (b << 7) + (int)d;
        if (g >= N_NODES) continue;
        uint4 xru = xr4[g * 8 + l];
        h2 xr[4] = {bch2(xru.x), bch2(xru.y), bch2(xru.z), bch2(xru.w)};
        uint4 xs = xl4[g * 8 + l];

        float q = edge_score8(xs, xr, at);
        q += __shfl_xor(q, 1); q += __shfl_xor(q, 2); q += __shfl_xor(q, 4);
        float S = fexp2(q);                     // scores bounded: raw exp safe
        float2 O[4] = {{0.f, 0.f}, {0.f, 0.f}, {0.f, 0.f}, {0.f, 0.f}};
        accum8(O, S, xs);

        unsigned j = dstart[d], jE = dstart[d + 1];
        if (j < jE) {
            uint4 vv = *(const uint4*)&srcsL[j];       // ds_read_b128, 16B-aligned
            uint4 c0v = xl4[(vv.x & 0x7FFFFFFFu) + l];
            uint4 c1v = xl4[(vv.y & 0x7FFFFFFFu) + l];
            uint4 c2v = xl4[(vv.z & 0x7FFFFFFFu) + l];
            uint4 c3v = xl4[(vv.w & 0x7FFFFFFFu) + l];
            for (;;) {
                j += 4;
                bool more = j < jE;
                uint4 nv, p0v, p1v, p2v, p3v;
                if (more) {
                    nv = *(const uint4*)&srcsL[j];
                    p0v = xl4[(nv.x & 0x7FFFFFFFu) + l];
                    p1v = xl4[(nv.y & 0x7FFFFFFFu) + l];
                    p2v = xl4[(nv.z & 0x7FFFFFFFu) + l];
                    p3v = xl4[(nv.w & 0x7FFFFFFFu) + l];
                }
                float p0 = edge_score8(c0v, xr, at);
                float p1 = edge_score8(c1v, xr, at);
                float p2 = edge_score8(c2v, xr, at);
                float p3 = edge_score8(c3v, xr, at);
                p0 += __shfl_xor(p0, 1); p0 += __shfl_xor(p0, 2); p0 += __shfl_xor(p0, 4);
                p1 += __shfl_xor(p1, 1); p1 += __shfl_xor(p1, 2); p1 += __shfl_xor(p1, 4);
                p2 += __shfl_xor(p2, 1); p2 += __shfl_xor(p2, 2); p2 += __shfl_xor(p2, 4);
                p3 += __shfl_xor(p3, 1); p3 += __shfl_xor(p3, 2); p3 += __shfl_xor(p3, 4);
                float w0 = (vv.x & 0x80000000u) ? 0.f : fexp2(p0);
                float w1 = (vv.y & 0x80000000u) ? 0.f : fexp2(p1);
                float w2 = (vv.z & 0x80000000u) ? 0.f : fexp2(p2);
                float w3 = (vv.w & 0x80000000u) ? 0.f : fexp2(p3);
                S += (w0 + w1) + (w2 + w3);
                accum8(O, w0, c0v);
                accum8(O, w1, c1v);
                accum8(O, w2, c2v);
                accum8(O, w3, c3v);
                if (!more) break;
                vv = nv; c0v = p0v; c1v = p1v; c2v = p2v; c3v = p3v;
            }
        }
        float inv = 1.f / (S + 1e-16f);
        size_t base = (size_t)g * 160 + col0 + c0;
#pragma unroll
        for (int i = 0; i < 4; ++i) {
            int cc = c0 + 2 * i;
            if (cc + 1 < D_OUT) {
                float blo = bo[cc], bhi = bo[cc + 1];
                float vlo = lrelu(O[i].x * inv + blo, 0.1f);
                float vhi = lrelu(O[i].y * inv + bhi, 0.1f);
                *(__half2*)&h16[base + 2 * i] = __floats2half2_rn(vlo, vhi);
            }
        }
    }
}

// ---------------- fused MFMA MLP head, wave-independent 16-node tiles ------------
#define HS 168

template<int NOT, int NKS, bool ACT>
__device__ __forceinline__ void head_layer(
    const _Float16* __restrict__ in, _Float16* __restrict__ outp,
    const unsigned short* __restrict__ wp, const float* __restrict__ bias, int l)
{
    const int lm = l & 15, q = l >> 4;
    const _Float16* aBase = in + lm * HS + q * 8;
#pragma unroll
    for (int ot = 0; ot < NOT; ++ot) {
        float4v acc = {0.f, 0.f, 0.f, 0.f};
        const unsigned short* bBase = wp + (ot * NKS) * 512 + l * 8;
#pragma unroll
        for (int ks = 0; ks < NKS; ++ks) {
            half8 a = *(const half8*)(aBase + ks * 32);
            half8 b = *(const half8*)(bBase + ks * 512);
            acc = __builtin_amdgcn_mfma_f32_16x16x32_f16(a, b, acc, 0, 0, 0);
        }
        float bv = bias[ot * 16 + lm];
#pragma unroll
        for (int r = 0; r < 4; ++r) {
            float v = acc[r] + bv;
            if (ACT) v = lrelu(v, 0.1f);
            outp[(q * 4 + r) * HS + ot * 16 + lm] = (_Float16)v;
        }
    }
}

__global__ __launch_bounds__(256) void mfma_head_kernel(
    const __half* __restrict__ h16,
    const unsigned short* __restrict__ wpkAll, const float* __restrict__ biasPad,
    float* __restrict__ out)
{
    __shared__ _Float16 sIn[4][16 * HS];
    __shared__ _Float16 sOut[4][16 * HS];
    int tid = threadIdx.x;
    int w = tid >> 6, l = tid & 63;
    int g0 = blockIdx.x * 64 + w * 16;

    const uint2* hq = (const uint2*)h16;
    for (int idx = l; idx < 16 * 42; idx += 64) {
        int row = idx / 42, qc = idx - row * 42;
        int gn = g0 + row;
        uint2 u = {0u, 0u};
        if (gn < N_NODES && qc < 40) {
            u = hq[(size_t)gn * 40 + qc];
            if (qc == 37) u.y = 0u;
            else if (qc > 37) { u.x = 0u; u.y = 0u; }
        }
        *(uint2*)&sIn[w][row * HS + qc * 4] = u;
    }
    __syncthreads();
    head_layer<10, 5, false>(sIn[w], sOut[w], wpkAll,         biasPad + 0,   l);
    __syncthreads();
    head_layer<6, 5, true >(sOut[w], sIn[w], wpkAll + 25600,  biasPad + 160, l);
    __syncthreads();
    head_layer<2, 3, true >(sIn[w], sOut[w], wpkAll + 40960,  biasPad + 256, l);
    __syncthreads();
    {
        const int lm = l & 15, q = l >> 4;
        float4v acc = {0.f, 0.f, 0.f, 0.f};
        half8 a = *(const half8*)(sOut[w] + lm * HS + q * 8);
        half8 b = *(const half8*)(wpkAll + 44032 + l * 8);
        acc = __builtin_amdgcn_mfma_f32_16x16x32_f16(a, b, acc, 0, 0, 0);
        if (lm < 2) {
            float bv = biasPad[288 + lm];
#pragma unroll
            for (int r = 0; r < 4; ++r) {
                int node = g0 + q * 4 + r;
                if (node < N_NODES) out[node * 2 + lm] = acc[r] + bv;
            }
        }
    }
}

extern "C" void kernel_launch(void* const* d_in, const int* in_sizes, int n_in,
                              void* d_out, int out_size, void* d_ws, size_t ws_size,
                              hipStream_t stream)
{
    const float* x = (const float*)d_in[0];
    const int* eip = (const int*)d_in[1];
    const int* eis = (const int*)d_in[2];
    const int* eiv = (const int*)d_in[3];
    const float *Wl[3], *bl[3], *Wr[3], *br[3], *att[3], *bo[3];
    for (int t = 0; t < 3; ++t) {
        int b = 4 + t * 6;
        Wl[t] = (const float*)d_in[b + 0];
        bl[t] = (const float*)d_in[b + 1];
        Wr[t] = (const float*)d_in[b + 2];
        br[t] = (const float*)d_in[b + 3];
        att[t] = (const float*)d_in[b + 4];
        bo[t] = (const float*)d_in[b + 5];
    }
    const float* projW = (const float*)d_in[22];
    const float* projb = (const float*)d_in[23];
    const float* W1 = (const float*)d_in[24];
    const float* b1 = (const float*)d_in[25];
    const float* W2 = (const float*)d_in[26];
    const float* b2 = (const float*)d_in[27];
    const float* W3 = (const float*)d_in[28];
    const float* b3 = (const float*)d_in[29];
    float* out = (float*)d_out;

    char* ws = (char*)d_ws;
    size_t off = 0;
    auto alloc = [&](size_t bytes) -> char* {
        char* p = ws + off;
        off += (bytes + 255) & ~(size_t)255;
        return p;
    };
    // xl3 has one extra zero row at absolute row index 3*N_NODES (dummy target)
    __half* xl3 = (__half*)alloc(((size_t)3 * N_NODES * 64 + 64) * 2);  // 38.4 MB
    __half* xr3 = (__half*)alloc((size_t)3 * N_NODES * 64 * 2);         // 38.4 MB
    unsigned* bucketed3 = (unsigned*)alloc((size_t)3 * NBKT * BSTR * 4); // 24 MB
    unsigned* bcur3 = (unsigned*)alloc((size_t)3 * NBKT * 4);
    __half* h16 = (__half*)alloc((size_t)N_NODES * 160 * 2);            // 32 MB
    unsigned short* wpkAll = (unsigned short*)alloc(56832 * 2);
    float* biasPad = (float*)alloc(688 * 4);

    (void)hipMemsetAsync(bcur3, 0, (size_t)3 * NBKT * 4, stream);
    pack_all_kernel<<<226, 256, 0, stream>>>(
        projW, W1, W2, W3, projb, b1, b2, b3,
        Wl[0], Wr[0], Wl[1], Wr[1], Wl[2], Wr[2],
        bl[0], br[0], bl[1], br[1], bl[2], br[2],
        wpkAll, biasPad, xl3);

    bkt_scatter_kernel<<<dim3(NBLK_E, 3), 256, 0, stream>>>(eip, eis, eiv, bcur3, bucketed3);

    transform_mfma_kernel<<<(N_NODES + 63) / 64, 256, 0, stream>>>(
        x, wpkAll, biasPad, xl3, xr3);

    bkt_gat_kernel<<<dim3(NBKT, 3), 256, 0, stream>>>(
        bucketed3, bcur3, xl3, xr3,
        att[0], att[1], att[2], bo[0], bo[1], bo[2], h16);

    mfma_head_kernel<<<(N_NODES + 63) / 64, 256, 0, stream>>>(h16, wpkAll, biasPad, out);
}